// Round 12
// baseline (107.472 us; speedup 1.0000x reference)
//
#include <hip/hip_runtime.h>
#include <hip/hip_bf16.h>

#define EF 128
#define KNN 8

typedef __attribute__((ext_vector_type(8)))  short          short8;
typedef __attribute__((ext_vector_type(8)))  unsigned short ushort8;
typedef __attribute__((ext_vector_type(4)))  float          f32x4;
typedef __attribute__((ext_vector_type(16))) float          f32x16;

// software round-to-nearest-even f32 -> bf16 bits (cold paths)
static __device__ __forceinline__ unsigned short f2bf(float f) {
    unsigned int x = __float_as_uint(f);
    unsigned int r = x + 0x7fffu + ((x >> 16) & 1u);
    return (unsigned short)(r >> 16);
}
// sanctioned compiler conversion (RNE) for hot paths
static __device__ __forceinline__ short f2bf_hw(float f) {
    return (short)__bfloat16_as_ushort(__float2bfloat16(f));
}
// pack two f32 into one u32 of 2x bf16 (lo = a, hi = b)
static __device__ __forceinline__ unsigned int pk2bf(float a, float b) {
    return (unsigned int)(unsigned short)f2bf_hw(a)
         | ((unsigned int)(unsigned short)f2bf_hw(b) << 16);
}

// ---------------------------------------------------------------------------
// pack_kernel:
//   W1[:128] -> W1p, 32x32x16 B-frag order (zgemm):
//     s = (((kt*4+nt)*64+l)*8+j); k = kt*16+(l>>5)*8+j; n = nt*32+(l&31)
//   W2      -> W2p, 16x16x32 B-frag order (edge kernel):
//     s = (((kt*8+nt)*64+l)*8+j); k = kt*32+(l>>4)*8+j; n = nt*16+(l&15)
// ---------------------------------------------------------------------------
__global__ __launch_bounds__(256) void pack_kernel(
    const float* __restrict__ W1, const float* __restrict__ W2,
    unsigned short* __restrict__ W1p, unsigned short* __restrict__ W2p)
{
    int t = blockIdx.x * 256 + threadIdx.x;
    if (t < 16384) {
        int s = t;
        int j  = s & 7;
        int l  = (s >> 3) & 63;
        int nt = (s >> 9) & 3;
        int kt = (s >> 11) & 7;
        int k = kt * 16 + (l >> 5) * 8 + j;
        int n = nt * 32 + (l & 31);
        W1p[s] = f2bf(W1[k * EF + n]);
    } else if (t < 32768) {
        int s = t - 16384;
        int j  = s & 7;
        int l  = (s >> 3) & 63;
        int nt = (s >> 9) & 7;
        int kt = (s >> 12) & 3;
        int k = kt * 32 + (l >> 4) * 8 + j;
        int n = nt * 16 + (l & 15);
        W2p[s] = f2bf(W2[k * EF + n]);
    }
}

// ---------------------------------------------------------------------------
// zgemm_kernel: Z[p][d] = bf16( b1[d] + sum_k input[p][k] * W1[k][d] )
// (unchanged 32x32x16 structure, verified rounds 2/5/7/8/9/11)
// ---------------------------------------------------------------------------
__global__ __launch_bounds__(256) void zgemm_kernel(
    const float* __restrict__ input,
    const unsigned short* __restrict__ W1p,
    const float* __restrict__ b1,
    unsigned short* __restrict__ Z,
    int npts, int ntiles)
{
    int l = threadIdx.x & 63;
    int tile = blockIdx.x * 4 + (threadIdx.x >> 6);
    if (tile >= ntiles) return;
    int p0   = tile * 32;
    int r    = l & 31;
    int half = l >> 5;
    int prow = p0 + r;
    if (prow >= npts) prow = npts - 1;      // clamp for ragged tail (reads only)
    const float* Arow = input + (size_t)prow * EF;

    f32x16 acc[4];
#pragma unroll
    for (int nt = 0; nt < 4; ++nt)
#pragma unroll
        for (int i = 0; i < 16; ++i) acc[nt][i] = 0.f;

#pragma unroll
    for (int kt = 0; kt < 8; ++kt) {
        int k0 = kt * 16 + half * 8;
        float4 a0 = *(const float4*)(Arow + k0);
        float4 a1 = *(const float4*)(Arow + k0 + 4);
        short8 a;
        a[0] = f2bf_hw(a0.x); a[1] = f2bf_hw(a0.y);
        a[2] = f2bf_hw(a0.z); a[3] = f2bf_hw(a0.w);
        a[4] = f2bf_hw(a1.x); a[5] = f2bf_hw(a1.y);
        a[6] = f2bf_hw(a1.z); a[7] = f2bf_hw(a1.w);
#pragma unroll
        for (int nt = 0; nt < 4; ++nt) {
            short8 b = *(const short8*)(W1p + ((size_t)((kt * 4 + nt) * 64 + l)) * 8);
            acc[nt] = __builtin_amdgcn_mfma_f32_32x32x16_bf16(a, b, acc[nt], 0, 0, 0);
        }
    }

    int col = l & 31;
#pragma unroll
    for (int nt = 0; nt < 4; ++nt) {
        float bb = b1[nt * 32 + col];
#pragma unroll
        for (int reg = 0; reg < 16; ++reg) {
            int row = (reg & 3) + 8 * (reg >> 2) + 4 * half;
            int p = p0 + row;
            if (p < npts)
                Z[(size_t)p * EF + nt * 32 + col] = f2bf(acc[nt][reg] + bb);
        }
    }
}

// ---------------------------------------------------------------------------
// edge_mfma_kernel (16x16x32, DUAL A-fragment): per wave a 32-edge tile
// (= 4 points) as two 16-row A-frags sharing every B-frag ds_read (halves
// W2 LDS traffic per edge). xyz weights held in 48 packed-bf16 VGPRs per
// lane (no LDS reads for weights at all). W2 staged in LDS once per block.
// ---------------------------------------------------------------------------
__global__ __launch_bounds__(512) void edge_mfma_kernel(
    const unsigned short* __restrict__ Z,
    const int* __restrict__ knn_idx,
    const float* __restrict__ knn_xyz,
    const unsigned short* __restrict__ W2p,
    const float* __restrict__ W1,       // xyz rows at +128*EF (f32)
    const float* __restrict__ b2,
    float* __restrict__ out,
    int npts, int nedges, int ntiles)
{
    __shared__ short8 w2lds[2048];      // 32 KB: full packed W2, frag order

    // ---- stage W2 fragments into LDS (once per block) ---------------------
    {
        const short8* W2v = (const short8*)W2p;
#pragma unroll
        for (int i = threadIdx.x; i < 2048; i += 512)
            w2lds[i] = W2v[i];
    }

    int l  = threadIdx.x & 63;
    int r  = l & 15;                    // edge row within fragment
    int hi = l >> 4;                    // k-group 0..3
    int tile = blockIdx.x * 8 + (threadIdx.x >> 6);
    bool active = tile < ntiles;

    // ---- hoist this lane's xyz weights into packed-bf16 registers ---------
    // lane touches d = kt*32 + hi*8 + j (kt 0..3, j 0..7): 32 d-values x 3.
    unsigned int wxp[4][4], wyp[4][4], wzp[4][4];   // [kt][pair], static idx
    {
        const float* W1x = W1 + EF * EF;
#pragma unroll
        for (int kt = 0; kt < 4; ++kt) {
            int d0 = kt * 32 + hi * 8;
            float4 xa = *(const float4*)(W1x + 0 * EF + d0);
            float4 xb = *(const float4*)(W1x + 0 * EF + d0 + 4);
            float4 ya = *(const float4*)(W1x + 1 * EF + d0);
            float4 yb = *(const float4*)(W1x + 1 * EF + d0 + 4);
            float4 za = *(const float4*)(W1x + 2 * EF + d0);
            float4 zb = *(const float4*)(W1x + 2 * EF + d0 + 4);
            wxp[kt][0] = pk2bf(xa.x, xa.y); wxp[kt][1] = pk2bf(xa.z, xa.w);
            wxp[kt][2] = pk2bf(xb.x, xb.y); wxp[kt][3] = pk2bf(xb.z, xb.w);
            wyp[kt][0] = pk2bf(ya.x, ya.y); wyp[kt][1] = pk2bf(ya.z, ya.w);
            wyp[kt][2] = pk2bf(yb.x, yb.y); wyp[kt][3] = pk2bf(yb.z, yb.w);
            wzp[kt][0] = pk2bf(za.x, za.y); wzp[kt][1] = pk2bf(za.z, za.w);
            wzp[kt][2] = pk2bf(zb.x, zb.y); wzp[kt][3] = pk2bf(zb.z, zb.w);
        }
    }

    // ---- per-edge meta + scattered gathers (2 edges per lane) -------------
    int eA = tile * 32 + r;             // frag0: edges 0..15 of tile
    int eB = tile * 32 + 16 + r;        // frag1: edges 16..31
    if (!active) { eA = 0; eB = 0; }
    if (eA >= nedges) eA = nedges - 1;
    if (eB >= nedges) eB = nedges - 1;

    int   iA = knn_idx[eA],            iB = knn_idx[eB];
    float xA = knn_xyz[eA * 3 + 0],    xB = knn_xyz[eB * 3 + 0];
    float yA = knn_xyz[eA * 3 + 1],    yB = knn_xyz[eB * 3 + 1];
    float zA = knn_xyz[eA * 3 + 2],    zB = knn_xyz[eB * 3 + 2];
    const unsigned short* ZrA = Z + (size_t)iA * EF;
    const unsigned short* ZrB = Z + (size_t)iB * EF;

    ushort8 zvA[4], zvB[4];
#pragma unroll
    for (int kt = 0; kt < 4; ++kt) {
        zvA[kt] = *(const ushort8*)(ZrA + kt * 32 + hi * 8);
        zvB[kt] = *(const ushort8*)(ZrB + kt * 32 + hi * 8);
    }

    __syncthreads();                    // w2lds ready (after gathers issued)
    if (!active) return;

    f32x4 acc0[8], acc1[8];
#pragma unroll
    for (int nt = 0; nt < 8; ++nt)
#pragma unroll
        for (int i = 0; i < 4; ++i) { acc0[nt][i] = 0.f; acc1[nt][i] = 0.f; }

#pragma unroll
    for (int kt = 0; kt < 4; ++kt) {
        short8 a0, a1;
#pragma unroll
        for (int jj = 0; jj < 4; ++jj) {
            unsigned int wxu = wxp[kt][jj];
            unsigned int wyu = wyp[kt][jj];
            unsigned int wzu = wzp[kt][jj];
            float wx0 = __uint_as_float(wxu << 16);
            float wx1 = __uint_as_float(wxu & 0xffff0000u);
            float wy0 = __uint_as_float(wyu << 16);
            float wy1 = __uint_as_float(wyu & 0xffff0000u);
            float wz0 = __uint_as_float(wzu << 16);
            float wz1 = __uint_as_float(wzu & 0xffff0000u);

            float h0 = __uint_as_float(((unsigned int)zvA[kt][2 * jj + 0]) << 16);
            float h1 = __uint_as_float(((unsigned int)zvA[kt][2 * jj + 1]) << 16);
            h0 = fmaf(xA, wx0, h0); h1 = fmaf(xA, wx1, h1);
            h0 = fmaf(yA, wy0, h0); h1 = fmaf(yA, wy1, h1);
            h0 = fmaf(zA, wz0, h0); h1 = fmaf(zA, wz1, h1);
            h0 = fmaxf(h0, 0.01f * h0); h1 = fmaxf(h1, 0.01f * h1);
            a0[2 * jj + 0] = f2bf_hw(h0); a0[2 * jj + 1] = f2bf_hw(h1);

            float g0 = __uint_as_float(((unsigned int)zvB[kt][2 * jj + 0]) << 16);
            float g1 = __uint_as_float(((unsigned int)zvB[kt][2 * jj + 1]) << 16);
            g0 = fmaf(xB, wx0, g0); g1 = fmaf(xB, wx1, g1);
            g0 = fmaf(yB, wy0, g0); g1 = fmaf(yB, wy1, g1);
            g0 = fmaf(zB, wz0, g0); g1 = fmaf(zB, wz1, g1);
            g0 = fmaxf(g0, 0.01f * g0); g1 = fmaxf(g1, 0.01f * g1);
            a1[2 * jj + 0] = f2bf_hw(g0); a1[2 * jj + 1] = f2bf_hw(g1);
        }
#pragma unroll
        for (int nt = 0; nt < 8; ++nt) {
            short8 b = w2lds[(kt * 8 + nt) * 64 + l];   // ONE ds_read, 2 MFMAs
            acc0[nt] = __builtin_amdgcn_mfma_f32_16x16x32_bf16(a0, b, acc0[nt], 0, 0, 0);
            acc1[nt] = __builtin_amdgcn_mfma_f32_16x16x32_bf16(a1, b, acc1[nt], 0, 0, 0);
        }
    }

    // ---- max-pool epilogue: frag0 -> points tile*4+{0,1}, frag1 -> +{2,3} -
    int col = l & 15;
    int p0  = tile * 4;
#pragma unroll
    for (int nt = 0; nt < 8; ++nt) {
        float bb = b2[nt * 16 + col];
        float m0 = fmaxf(fmaxf(acc0[nt][0], acc0[nt][1]),
                         fmaxf(acc0[nt][2], acc0[nt][3]));
        m0 = fmaxf(m0, __shfl_xor(m0, 16));
        float m1 = fmaxf(fmaxf(acc1[nt][0], acc1[nt][1]),
                         fmaxf(acc1[nt][2], acc1[nt][3]));
        m1 = fmaxf(m1, __shfl_xor(m1, 16));
        if (!(hi & 1)) {
            int pa = p0 + (hi >> 1);
            int pb = p0 + 2 + (hi >> 1);
            if (pa < npts) out[(size_t)pa * EF + nt * 16 + col] = m0 + bb;
            if (pb < npts) out[(size_t)pb * EF + nt * 16 + col] = m1 + bb;
        }
    }
}

extern "C" void kernel_launch(void* const* d_in, const int* in_sizes, int n_in,
                              void* d_out, int out_size, void* d_ws, size_t ws_size,
                              hipStream_t stream) {
    const float* input   = (const float*)d_in[0];
    const int*   knn_idx = (const int*)  d_in[1];
    const float* knn_xyz = (const float*)d_in[2];
    const float* W1      = (const float*)d_in[3];
    const float* b1      = (const float*)d_in[4];
    const float* W2      = (const float*)d_in[5];
    const float* b2      = (const float*)d_in[6];
    float*       out     = (float*)d_out;

    int npts   = in_sizes[0] / EF;          // 100000
    int nedges = in_sizes[1];               // npts * 8

    // workspace layout
    unsigned short* W1p = (unsigned short*)d_ws;                  // 16384
    unsigned short* W2p = W1p + 16384;                            // 16384
    unsigned short* Z   = (unsigned short*)((char*)d_ws + 65536); // npts*128

    pack_kernel<<<128, 256, 0, stream>>>(W1, W2, W1p, W2p);

    int ztiles = (npts + 31) / 32;
    zgemm_kernel<<<(ztiles + 3) / 4, 256, 0, stream>>>(
        input, W1p, b1, Z, npts, ztiles);

    int etiles = (nedges + 31) / 32;        // 32 edges per wave now
    int eblocks = (etiles + 7) / 8;         // 8 waves per block
    edge_mfma_kernel<<<eblocks, 512, 0, stream>>>(
        Z, knn_idx, knn_xyz, W2p, W1, b2, out, npts, nedges, etiles);
}